// Round 13
// baseline (199.108 us; speedup 1.0000x reference)
//
#include <hip/hip_runtime.h>
#include <math.h>

// GAT single layer: N=100000, E=1.6M, F_IN=128, H=8, C=16 (HC=128)
// R13: two-pass binned CSR build (k_bin: single scan -> 8 per-XCD staging
// lists; k_scat2: each residue drains its own list, XCD-local writes).
// k_aggr back to 256-thread blocks (R12's 512 regressed occupancy).

#define KCAP 32
#define OVF_CAP 65536
#define BCAP 250000   // per-residue staging capacity (E[res]=200K, +120 sigma)

typedef __attribute__((ext_vector_type(8))) short short8;    // 8 bf16 (4 VGPR)
typedef __attribute__((ext_vector_type(4))) float f32x4;     // MFMA acc

__device__ __forceinline__ float lrelu(float x) { return x > 0.f ? x : 0.2f * x; }

__device__ __forceinline__ unsigned short f2bf(float f) {   // RNE
    unsigned u = __float_as_uint(f);
    unsigned r = u + 0x7FFFu + ((u >> 16) & 1u);
    return (unsigned short)(r >> 16);
}
__device__ __forceinline__ float bflo(unsigned v) { return __uint_as_float(v << 16); }
__device__ __forceinline__ float bfhi(unsigned v) { return __uint_as_float(v & 0xffff0000u); }

// ---------------- prep: Wcat[144][128] bf16 + zero count/ovfc/chunkc ----------------
__global__ void k_prep(const float* __restrict__ W, const float* __restrict__ att_src,
                       const float* __restrict__ att_dst, unsigned short* __restrict__ wtg,
                       int* __restrict__ count, int N) {
    int t = blockIdx.x * blockDim.x + threadIdx.x;
    if (t <= N + 8) count[t] = 0;      // count[N]=ovfc, count[N+1..N+8]=chunkc[8]
    if (t >= 144 * 128) return;
    int row = t >> 7, k = t & 127;
    float val;
    if (row < 128) {
        val = W[k * 128 + row];                       // transpose
    } else if (row < 136) {
        int h = row - 128; val = 0.f;
#pragma unroll
        for (int c = 0; c < 16; ++c) val += W[k * 128 + h * 16 + c] * att_src[h * 16 + c];
    } else {
        int h = row - 136; val = 0.f;
#pragma unroll
        for (int c = 0; c < 16; ++c) val += W[k * 128 + h * 16 + c] * att_dst[h * 16 + c];
    }
    wtg[row * 128 + k] = f2bf(val);
}

// ---------------- MFMA GEMM: 128 rows/block (2 row-tiles per LDS stage) ----------------
__global__ __launch_bounds__(256) void k_gemm(const float* __restrict__ x,
                                              const unsigned* __restrict__ wtg4,
                                              unsigned* __restrict__ xpb,
                                              float* __restrict__ a_src,
                                              float* __restrict__ a_dst, int N) {
    __shared__ __align__(16) unsigned short Wl[144 * 136];   // +8 bf16 pad per row

    int tid = threadIdx.x;
    uint4* l4 = (uint4*)Wl;
    const uint4* g4 = (const uint4*)wtg4;
#pragma unroll
    for (int it = 0; it < 9; ++it) {
        int idx = tid + it * 256;          // < 2304
        int row = idx >> 4, c = idx & 15;
        l4[row * 17 + c] = g4[idx];
    }
    __syncthreads();

    int w = tid >> 6, lane = tid & 63;
    int col = lane & 15, grp = lane >> 4;

#pragma unroll 1
    for (int rt = 0; rt < 2; ++rt) {
        int r0 = blockIdx.x * 128 + rt * 64 + w * 16;
        if (r0 >= N) break;                // wave-uniform; no barriers inside loop
        int arow = r0 + col;
        int arc = arow < N ? arow : N - 1;

        f32x4 acc[9];
#pragma unroll
        for (int t = 0; t < 9; ++t) acc[t] = (f32x4){0.f, 0.f, 0.f, 0.f};

#pragma unroll
        for (int kk = 0; kk < 4; ++kk) {
            int k0 = kk * 32 + grp * 8;
            float4 xa = *(const float4*)&x[(long)arc * 128 + k0];
            float4 xb = *(const float4*)&x[(long)arc * 128 + k0 + 4];
            short8 a;
            a[0] = (short)f2bf(xa.x); a[1] = (short)f2bf(xa.y);
            a[2] = (short)f2bf(xa.z); a[3] = (short)f2bf(xa.w);
            a[4] = (short)f2bf(xb.x); a[5] = (short)f2bf(xb.y);
            a[6] = (short)f2bf(xb.z); a[7] = (short)f2bf(xb.w);
#pragma unroll
            for (int t = 0; t < 9; ++t) {
                short8 b = *(const short8*)&Wl[(t * 16 + col) * 136 + k0];
                acc[t] = __builtin_amdgcn_mfma_f32_16x16x32_bf16(a, b, acc[t], 0, 0, 0);
            }
        }

        // epilogue: tiles 0-7 -> packed bf16 xpb; tile 8 -> a_src/a_dst
#pragma unroll
        for (int t = 0; t < 8; ++t) {
#pragma unroll
            for (int reg = 0; reg < 4; ++reg) {
                float mine = acc[t][reg];
                float oth = __shfl_xor(mine, 1);
                unsigned mb = f2bf(mine), ob = f2bf(oth);
                unsigned dw = (lane & 1) ? (ob | (mb << 16)) : (mb | (ob << 16));
                if (((lane & 1) == 0 && reg < 2) || ((lane & 1) == 1 && reg >= 2)) {
                    int grow = r0 + grp * 4 + reg;
                    if (grow < N) xpb[(unsigned)grow * 64 + t * 8 + (col >> 1)] = dw;
                }
            }
        }
#pragma unroll
        for (int reg = 0; reg < 4; ++reg) {
            int grow = r0 + grp * 4 + reg;
            if (grow < N) {
                float v = acc[8][reg];
                if (col < 8) a_src[(unsigned)grow * 8 + col] = v;
                else         a_dst[(unsigned)grow * 8 + (col - 8)] = v;
            }
        }
    }
}

// ---------------- pass A: single-scan binning into 8 per-residue lists ----------------
__global__ __launch_bounds__(256) void k_bin(const int* __restrict__ ei,
                                             int* __restrict__ chunkc,
                                             int2* __restrict__ binbuf,
                                             int* __restrict__ count,
                                             int* __restrict__ bucket,
                                             int* __restrict__ ovfc,
                                             int* __restrict__ ovf,
                                             int E, int pw8) {
    __shared__ int lcnt[8];
    __shared__ int lbase[8];
    int tid = threadIdx.x;
    long base = (long)blockIdx.x * 1024;
    if (base >= E) return;
    if (tid < 8) lcnt[tid] = 0;
    __syncthreads();

    long e0 = base + tid * 4;
    int sv[4], dv[4], res[4], rnk[4];
    int nval = 0;
    if (e0 + 4 <= E) {
        int4 s4 = *(const int4*)&ei[e0];
        int4 d4 = *(const int4*)&ei[E + e0];
        sv[0] = s4.x; sv[1] = s4.y; sv[2] = s4.z; sv[3] = s4.w;
        dv[0] = d4.x; dv[1] = d4.y; dv[2] = d4.z; dv[3] = d4.w;
        nval = 4;
    } else {
        for (long c = 0; e0 + c < E; ++c) {
            sv[nval] = ei[e0 + c];
            dv[nval] = ei[E + e0 + c];
            nval++;
        }
    }
#pragma unroll
    for (int c = 0; c < 4; ++c) {
        if (c < nval) {
            int r = dv[c] / pw8;             // 0..7
            res[c] = r;
            rnk[c] = atomicAdd(&lcnt[r], 1);
        }
    }
    __syncthreads();
    if (tid < 8) lbase[tid] = atomicAdd(&chunkc[tid], lcnt[tid]);
    __syncthreads();
#pragma unroll
    for (int c = 0; c < 4; ++c) {
        if (c < nval) {
            int r = res[c];
            int pos = lbase[r] + rnk[c];
            if (pos < BCAP) {
                binbuf[(long)r * BCAP + pos] = make_int2(sv[c], dv[c]);
            } else {                          // fallback: direct scatter (never in practice)
                int d = dv[c];
                int slot = atomicAdd(&count[d], 1);
                if (slot < KCAP) bucket[(unsigned)d * KCAP + slot] = sv[c];
                else { int o = atomicAdd(ovfc, 1);
                       if (o < OVF_CAP) { ovf[2 * o] = d; ovf[2 * o + 1] = sv[c]; } }
            }
        }
    }
}

// ---------------- pass B: each residue drains its own list (XCD-local writes) ----------------
__global__ __launch_bounds__(256) void k_scat2(const int2* __restrict__ binbuf,
                                               const int* __restrict__ chunkc,
                                               int* __restrict__ count,
                                               int* __restrict__ bucket,
                                               int* __restrict__ ovfc,
                                               int* __restrict__ ovf) {
    int res = blockIdx.x & 7;
    int sub = blockIdx.x >> 3;
    int nsub = gridDim.x >> 3;
    int n = chunkc[res]; if (n > BCAP) n = BCAP;
    const int2* buf = &binbuf[(long)res * BCAP];
    int stride = nsub * blockDim.x;
    for (int i = sub * blockDim.x + threadIdx.x; i < n; i += stride) {
        int2 sd = buf[i];
        int slot = atomicAdd(&count[sd.y], 1);
        if (slot < KCAP) {
            bucket[(unsigned)sd.y * KCAP + slot] = sd.x;
        } else {
            int o = atomicAdd(ovfc, 1);
            if (o < OVF_CAP) { ovf[2 * o] = sd.y; ovf[2 * o + 1] = sd.x; }
        }
    }
}

// ---------------- fused softmax+aggregation: 16 lanes/edge, 4 nodes/block ----------------
__global__ __launch_bounds__(256) void k_aggr(const uint4* __restrict__ xpb4,
                                              const float* __restrict__ a_src,
                                              const float* __restrict__ a_dst,
                                              const int* __restrict__ count,
                                              const int* __restrict__ bucket,
                                              const int* __restrict__ ovfc,
                                              const int* __restrict__ ovf,
                                              const float* __restrict__ bias,
                                              float* __restrict__ out, int N, int pw8) {
    int wv = threadIdx.x >> 6, lane = threadIdx.x & 63;
    int res = blockIdx.x & 7, sub = blockIdx.x >> 3;
    int nir = sub * 4 + wv;                  // node index within this residue's range
    if (nir >= pw8) return;
    int node = res * pw8 + nir;
    if (node >= N) return;

    int deg = count[node];
    const int* bk = &bucket[(unsigned)node * KCAP];

    int sg = lane >> 4, sl = lane & 15;      // subgroup (edge slot), sub-lane (feature block)
    int h = sl >> 1;                         // head for features sl*8..sl*8+7
    float adh = a_dst[(unsigned)node * 8 + h];

    float acc[8];
#pragma unroll
    for (int i = 0; i < 8; ++i) acc[i] = 0.f;
    float sm = 0.f;

    int dm = deg < KCAP ? deg : KCAP;
    int k = 0;
    for (; k + 16 <= dm; k += 16) {          // 16 edges: 4 per subgroup
        int e0 = bk[k + sg], e1 = bk[k + 4 + sg], e2 = bk[k + 8 + sg], e3 = bk[k + 12 + sg];
        uint4 v0 = xpb4[(unsigned)e0 * 16 + sl];
        uint4 v1 = xpb4[(unsigned)e1 * 16 + sl];
        uint4 v2 = xpb4[(unsigned)e2 * 16 + sl];
        uint4 v3 = xpb4[(unsigned)e3 * 16 + sl];
        float w0 = __expf(lrelu(a_src[(unsigned)e0 * 8 + h] + adh));
        float w1 = __expf(lrelu(a_src[(unsigned)e1 * 8 + h] + adh));
        float w2 = __expf(lrelu(a_src[(unsigned)e2 * 8 + h] + adh));
        float w3 = __expf(lrelu(a_src[(unsigned)e3 * 8 + h] + adh));
        sm += (w0 + w1) + (w2 + w3);
        acc[0] += w0 * bflo(v0.x) + w1 * bflo(v1.x) + w2 * bflo(v2.x) + w3 * bflo(v3.x);
        acc[1] += w0 * bfhi(v0.x) + w1 * bfhi(v1.x) + w2 * bfhi(v2.x) + w3 * bfhi(v3.x);
        acc[2] += w0 * bflo(v0.y) + w1 * bflo(v1.y) + w2 * bflo(v2.y) + w3 * bflo(v3.y);
        acc[3] += w0 * bfhi(v0.y) + w1 * bfhi(v1.y) + w2 * bfhi(v2.y) + w3 * bfhi(v3.y);
        acc[4] += w0 * bflo(v0.z) + w1 * bflo(v1.z) + w2 * bflo(v2.z) + w3 * bflo(v3.z);
        acc[5] += w0 * bfhi(v0.z) + w1 * bfhi(v1.z) + w2 * bfhi(v2.z) + w3 * bfhi(v3.z);
        acc[6] += w0 * bflo(v0.w) + w1 * bflo(v1.w) + w2 * bflo(v2.w) + w3 * bflo(v3.w);
        acc[7] += w0 * bfhi(v0.w) + w1 * bfhi(v1.w) + w2 * bfhi(v2.w) + w3 * bfhi(v3.w);
    }
    for (; k + 8 <= dm; k += 8) {            // 8 edges: 2 per subgroup
        int e0 = bk[k + sg], e1 = bk[k + 4 + sg];
        uint4 v0 = xpb4[(unsigned)e0 * 16 + sl];
        uint4 v1 = xpb4[(unsigned)e1 * 16 + sl];
        float w0 = __expf(lrelu(a_src[(unsigned)e0 * 8 + h] + adh));
        float w1 = __expf(lrelu(a_src[(unsigned)e1 * 8 + h] + adh));
        sm += w0 + w1;
        acc[0] += w0 * bflo(v0.x) + w1 * bflo(v1.x);
        acc[1] += w0 * bfhi(v0.x) + w1 * bfhi(v1.x);
        acc[2] += w0 * bflo(v0.y) + w1 * bflo(v1.y);
        acc[3] += w0 * bfhi(v0.y) + w1 * bfhi(v1.y);
        acc[4] += w0 * bflo(v0.z) + w1 * bflo(v1.z);
        acc[5] += w0 * bfhi(v0.z) + w1 * bfhi(v1.z);
        acc[6] += w0 * bflo(v0.w) + w1 * bflo(v1.w);
        acc[7] += w0 * bfhi(v0.w) + w1 * bfhi(v1.w);
    }
    for (; k < dm; k += 4) {                 // tail: up to 4 edges, masked per subgroup
        int e = k + sg;
        if (e < dm) {
            int s = bk[e];
            uint4 v = xpb4[(unsigned)s * 16 + sl];
            float w = __expf(lrelu(a_src[(unsigned)s * 8 + h] + adh));
            sm += w;
            acc[0] += w * bflo(v.x); acc[1] += w * bfhi(v.x);
            acc[2] += w * bflo(v.y); acc[3] += w * bfhi(v.y);
            acc[4] += w * bflo(v.z); acc[5] += w * bfhi(v.z);
            acc[6] += w * bflo(v.w); acc[7] += w * bfhi(v.w);
        }
    }
    if (deg > KCAP) {                        // rare overflow path
        int novf = *ovfc;
        if (novf > OVF_CAP) novf = OVF_CAP;
        for (int o = sg; o < novf; o += 4) {
            if (ovf[2 * o] == node) {
                int s = ovf[2 * o + 1];
                uint4 v = xpb4[(unsigned)s * 16 + sl];
                float w = __expf(lrelu(a_src[(unsigned)s * 8 + h] + adh));
                sm += w;
                acc[0] += w * bflo(v.x); acc[1] += w * bfhi(v.x);
                acc[2] += w * bflo(v.y); acc[3] += w * bfhi(v.y);
                acc[4] += w * bflo(v.z); acc[5] += w * bfhi(v.z);
                acc[6] += w * bflo(v.w); acc[7] += w * bfhi(v.w);
            }
        }
    }

    // combine the 4 subgroup partials (sl preserved under xor 16/32)
    sm += __shfl_xor(sm, 16);
    sm += __shfl_xor(sm, 32);
#pragma unroll
    for (int i = 0; i < 8; ++i) {
        acc[i] += __shfl_xor(acc[i], 16);
        acc[i] += __shfl_xor(acc[i], 32);
    }

    if (sg == 0) {
        float rd = 1.f / (sm + 1e-16f);
        int j = sl * 8;
        float4 b0 = *(const float4*)&bias[j];
        float4 b1 = *(const float4*)&bias[j + 4];
        *(float4*)&out[(unsigned)node * 128 + j] =
            make_float4(acc[0] * rd + b0.x, acc[1] * rd + b0.y, acc[2] * rd + b0.z, acc[3] * rd + b0.w);
        *(float4*)&out[(unsigned)node * 128 + j + 4] =
            make_float4(acc[4] * rd + b1.x, acc[5] * rd + b1.y, acc[6] * rd + b1.z, acc[7] * rd + b1.w);
    }
}

extern "C" void kernel_launch(void* const* d_in, const int* in_sizes, int n_in,
                              void* d_out, int out_size, void* d_ws, size_t ws_size,
                              hipStream_t stream) {
    const float* x = (const float*)d_in[0];
    const int* ei = (const int*)d_in[1];          // int32 (harness-converted)
    const float* W = (const float*)d_in[2];
    const float* att_src = (const float*)d_in[3];
    const float* att_dst = (const float*)d_in[4];
    const float* bias = (const float*)d_in[5];

    int N = in_sizes[0] / 128;   // 100000
    int E = in_sizes[1] / 2;     // 1600000
    float* out = (float*)d_out;

    int pw8 = (N + 7) / 8;       // 12500

    // ws layout (4B units): xpb[N*64] | a_src[N*8] | a_dst[N*8] | wtg[9216/2 dwords]
    //   | count[N] | ovfc[1] | chunkc[8] | ovf[2*OVF_CAP] | binbuf[8*BCAP int2] | bucket[N*KCAP]
    unsigned* xpb = (unsigned*)d_ws;
    float* a_src = (float*)(xpb + (size_t)N * 64);
    float* a_dst = a_src + (size_t)N * 8;
    unsigned short* wtg = (unsigned short*)(a_dst + (size_t)N * 8);
    int* count = (int*)(wtg + 144 * 128);
    int* ovfc = count + N;       // zeroed by k_prep
    int* chunkc = ovfc + 1;      // zeroed by k_prep
    int* ovf = chunkc + 8;
    int2* binbuf = (int2*)(ovf + 2 * OVF_CAP);
    int* bucket = (int*)(binbuf + (size_t)8 * BCAP);

    k_prep<<<463, 256, 0, stream>>>(W, att_src, att_dst, wtg, count, N);
    k_gemm<<<(N + 127) / 128, 256, 0, stream>>>(x, (const unsigned*)wtg, xpb, a_src, a_dst, N);
    k_bin<<<(E + 1023) / 1024, 256, 0, stream>>>(ei, chunkc, binbuf, count, bucket, ovfc, ovf, E, pw8);
    k_scat2<<<2048, 256, 0, stream>>>(binbuf, chunkc, count, bucket, ovfc, ovf);
    k_aggr<<<8 * ((pw8 + 3) / 4), 256, 0, stream>>>((const uint4*)xpb, a_src, a_dst, count,
                                                    bucket, ovfc, ovf, bias, out, N, pw8);
}

// Round 15
// 186.540 us; speedup vs baseline: 1.0674x; 1.0674x over previous
//
#include <hip/hip_runtime.h>
#include <math.h>

// GAT single layer: N=100000, E=1.6M, F_IN=128, H=8, C=16 (HC=128)
// R15: R14 with the att-row build bug fixed (h must span 0..7, i.e. 1024
// work items computing BOTH src/dst rows; R14's 2048 ran h to 15 and wrote
// past the 144-row LDS tile -> NaN).

#define KCAP 32
#define OVF_CAP 65536

typedef __attribute__((ext_vector_type(8))) short short8;    // 8 bf16 (4 VGPR)
typedef __attribute__((ext_vector_type(4))) float f32x4;     // MFMA acc

__device__ __forceinline__ float lrelu(float x) { return x > 0.f ? x : 0.2f * x; }

__device__ __forceinline__ unsigned short f2bf(float f) {   // RNE
    unsigned u = __float_as_uint(f);
    unsigned r = u + 0x7FFFu + ((u >> 16) & 1u);
    return (unsigned short)(r >> 16);
}
__device__ __forceinline__ float bflo(unsigned v) { return __uint_as_float(v << 16); }
__device__ __forceinline__ float bfhi(unsigned v) { return __uint_as_float(v & 0xffff0000u); }

// ---------------- MFMA GEMM with in-block Wcat build + count zeroing ----------------
__global__ __launch_bounds__(256) void k_gemm(const float* __restrict__ x,
                                              const float* __restrict__ W,
                                              const float* __restrict__ att_src,
                                              const float* __restrict__ att_dst,
                                              unsigned* __restrict__ xpb,
                                              float* __restrict__ a_src,
                                              float* __restrict__ a_dst,
                                              int* __restrict__ count, int N) {
    __shared__ __align__(16) unsigned short Wl[144 * 136];   // +8 bf16 pad per row

    int tid = threadIdx.x;

    // zero count[0..N] + ovfc (count[N]) -- gemm grid covers N+1 thread ids
    {
        int g = blockIdx.x * 256 + tid;
        if (g <= N) count[g] = 0;
    }

    // stage W^T as bf16: W[k][j] -> Wl[j*136 + k]
    const float4* W4 = (const float4*)W;
#pragma unroll
    for (int it = 0; it < 16; ++it) {
        int idx = tid + it * 256;          // 4096 float4 total
        float4 v = W4[idx];
        int k = idx >> 5;                  // 32 float4 per W row
        int j0 = (idx & 31) * 4;
        Wl[(j0 + 0) * 136 + k] = f2bf(v.x);
        Wl[(j0 + 1) * 136 + k] = f2bf(v.y);
        Wl[(j0 + 2) * 136 + k] = f2bf(v.z);
        Wl[(j0 + 3) * 136 + k] = f2bf(v.w);
    }
    __syncthreads();

    // att rows: 1024 work items (k=0..127, h=0..7), each computes BOTH
    // row 128+h = (W@att_src)^T[h][k] and row 136+h = (W@att_dst)^T[h][k]
#pragma unroll
    for (int it = 0; it < 4; ++it) {
        int p = tid + it * 256;            // 0..1023
        int k = p & 127, h = p >> 7;       // h in 0..7
        float s1 = 0.f, s2 = 0.f;
#pragma unroll
        for (int c = 0; c < 16; ++c) {
            float wv = __uint_as_float((unsigned)Wl[(h * 16 + c) * 136 + k] << 16);
            s1 += wv * att_src[h * 16 + c];
            s2 += wv * att_dst[h * 16 + c];
        }
        Wl[(128 + h) * 136 + k] = f2bf(s1);
        Wl[(136 + h) * 136 + k] = f2bf(s2);
    }
    __syncthreads();

    int w = tid >> 6, lane = tid & 63;
    int col = lane & 15, grp = lane >> 4;

#pragma unroll 1
    for (int rt = 0; rt < 2; ++rt) {
        int r0 = blockIdx.x * 128 + rt * 64 + w * 16;
        if (r0 >= N) break;                // wave-uniform; no barriers inside loop
        int arow = r0 + col;
        int arc = arow < N ? arow : N - 1;

        f32x4 acc[9];
#pragma unroll
        for (int t = 0; t < 9; ++t) acc[t] = (f32x4){0.f, 0.f, 0.f, 0.f};

#pragma unroll
        for (int kk = 0; kk < 4; ++kk) {
            int k0 = kk * 32 + grp * 8;
            float4 xa = *(const float4*)&x[(long)arc * 128 + k0];
            float4 xb = *(const float4*)&x[(long)arc * 128 + k0 + 4];
            short8 a;
            a[0] = (short)f2bf(xa.x); a[1] = (short)f2bf(xa.y);
            a[2] = (short)f2bf(xa.z); a[3] = (short)f2bf(xa.w);
            a[4] = (short)f2bf(xb.x); a[5] = (short)f2bf(xb.y);
            a[6] = (short)f2bf(xb.z); a[7] = (short)f2bf(xb.w);
#pragma unroll
            for (int t = 0; t < 9; ++t) {
                short8 b = *(const short8*)&Wl[(t * 16 + col) * 136 + k0];
                acc[t] = __builtin_amdgcn_mfma_f32_16x16x32_bf16(a, b, acc[t], 0, 0, 0);
            }
        }

        // epilogue: tiles 0-7 -> packed bf16 xpb; tile 8 -> a_src/a_dst
#pragma unroll
        for (int t = 0; t < 8; ++t) {
#pragma unroll
            for (int reg = 0; reg < 4; ++reg) {
                float mine = acc[t][reg];
                float oth = __shfl_xor(mine, 1);
                unsigned mb = f2bf(mine), ob = f2bf(oth);
                unsigned dw = (lane & 1) ? (ob | (mb << 16)) : (mb | (ob << 16));
                if (((lane & 1) == 0 && reg < 2) || ((lane & 1) == 1 && reg >= 2)) {
                    int grow = r0 + grp * 4 + reg;
                    if (grow < N) xpb[(unsigned)grow * 64 + t * 8 + (col >> 1)] = dw;
                }
            }
        }
#pragma unroll
        for (int reg = 0; reg < 4; ++reg) {
            int grow = r0 + grp * 4 + reg;
            if (grow < N) {
                float v = acc[8][reg];
                if (col < 8) a_src[(unsigned)grow * 8 + col] = v;
                else         a_dst[(unsigned)grow * 8 + (col - 8)] = v;
            }
        }
    }
}

// ---------------- one-pass bucket build; blockIdx&7 owns dst range (XCD locality) ----------------
__global__ __launch_bounds__(256) void k_scatter(const int* __restrict__ ei,
                                                 int* __restrict__ count,
                                                 int* __restrict__ bucket,
                                                 int* __restrict__ ovfc,
                                                 int* __restrict__ ovf,
                                                 int E, int pw8, int N) {
    int res = blockIdx.x & 7;
    int sub = blockIdx.x >> 3;
    int nsub = gridDim.x >> 3;
    int dlo = res * pw8, dhi = dlo + pw8;
    if (dhi > N) dhi = N;
    long stride = (long)nsub * blockDim.x * 4;
    for (long e = ((long)sub * blockDim.x + threadIdx.x) * 4; e < E; e += stride) {
        int4 d4 = *(const int4*)&ei[E + e];
        int4 s4 = *(const int4*)&ei[e];
#pragma unroll
        for (int c = 0; c < 4; ++c) {
            int d = (&d4.x)[c];
            if (d >= dlo && d < dhi) {
                int s = (&s4.x)[c];
                int slot = atomicAdd(&count[d], 1);
                if (slot < KCAP) {
                    bucket[(unsigned)d * KCAP + slot] = s;
                } else {
                    int o = atomicAdd(ovfc, 1);
                    if (o < OVF_CAP) { ovf[2 * o] = d; ovf[2 * o + 1] = s; }
                }
            }
        }
    }
}

// ---------------- fused softmax+aggregation: 16 lanes/edge, 4 nodes/block ----------------
__global__ __launch_bounds__(256) void k_aggr(const uint4* __restrict__ xpb4,
                                              const float* __restrict__ a_src,
                                              const float* __restrict__ a_dst,
                                              const int* __restrict__ count,
                                              const int* __restrict__ bucket,
                                              const int* __restrict__ ovfc,
                                              const int* __restrict__ ovf,
                                              const float* __restrict__ bias,
                                              float* __restrict__ out, int N, int pw8) {
    int wv = threadIdx.x >> 6, lane = threadIdx.x & 63;
    int res = blockIdx.x & 7, sub = blockIdx.x >> 3;
    int nir = sub * 4 + wv;                  // node index within this residue's range
    if (nir >= pw8) return;
    int node = res * pw8 + nir;
    if (node >= N) return;

    int deg = count[node];
    const int* bk = &bucket[(unsigned)node * KCAP];

    int sg = lane >> 4, sl = lane & 15;      // subgroup (edge slot), sub-lane (feature block)
    int h = sl >> 1;                         // head for features sl*8..sl*8+7
    float adh = a_dst[(unsigned)node * 8 + h];

    float acc[8];
#pragma unroll
    for (int i = 0; i < 8; ++i) acc[i] = 0.f;
    float sm = 0.f;

    int dm = deg < KCAP ? deg : KCAP;
    int k = 0;
    for (; k + 16 <= dm; k += 16) {          // 16 edges: 4 per subgroup
        int e0 = bk[k + sg], e1 = bk[k + 4 + sg], e2 = bk[k + 8 + sg], e3 = bk[k + 12 + sg];
        uint4 v0 = xpb4[(unsigned)e0 * 16 + sl];
        uint4 v1 = xpb4[(unsigned)e1 * 16 + sl];
        uint4 v2 = xpb4[(unsigned)e2 * 16 + sl];
        uint4 v3 = xpb4[(unsigned)e3 * 16 + sl];
        float w0 = __expf(lrelu(a_src[(unsigned)e0 * 8 + h] + adh));
        float w1 = __expf(lrelu(a_src[(unsigned)e1 * 8 + h] + adh));
        float w2 = __expf(lrelu(a_src[(unsigned)e2 * 8 + h] + adh));
        float w3 = __expf(lrelu(a_src[(unsigned)e3 * 8 + h] + adh));
        sm += (w0 + w1) + (w2 + w3);
        acc[0] += w0 * bflo(v0.x) + w1 * bflo(v1.x) + w2 * bflo(v2.x) + w3 * bflo(v3.x);
        acc[1] += w0 * bfhi(v0.x) + w1 * bfhi(v1.x) + w2 * bfhi(v2.x) + w3 * bfhi(v3.x);
        acc[2] += w0 * bflo(v0.y) + w1 * bflo(v1.y) + w2 * bflo(v2.y) + w3 * bflo(v3.y);
        acc[3] += w0 * bfhi(v0.y) + w1 * bfhi(v1.y) + w2 * bfhi(v2.y) + w3 * bfhi(v3.y);
        acc[4] += w0 * bflo(v0.z) + w1 * bflo(v1.z) + w2 * bflo(v2.z) + w3 * bflo(v3.z);
        acc[5] += w0 * bfhi(v0.z) + w1 * bfhi(v1.z) + w2 * bfhi(v2.z) + w3 * bfhi(v3.z);
        acc[6] += w0 * bflo(v0.w) + w1 * bflo(v1.w) + w2 * bflo(v2.w) + w3 * bflo(v3.w);
        acc[7] += w0 * bfhi(v0.w) + w1 * bfhi(v1.w) + w2 * bfhi(v2.w) + w3 * bfhi(v3.w);
    }
    for (; k + 8 <= dm; k += 8) {            // 8 edges: 2 per subgroup
        int e0 = bk[k + sg], e1 = bk[k + 4 + sg];
        uint4 v0 = xpb4[(unsigned)e0 * 16 + sl];
        uint4 v1 = xpb4[(unsigned)e1 * 16 + sl];
        float w0 = __expf(lrelu(a_src[(unsigned)e0 * 8 + h] + adh));
        float w1 = __expf(lrelu(a_src[(unsigned)e1 * 8 + h] + adh));
        sm += w0 + w1;
        acc[0] += w0 * bflo(v0.x) + w1 * bflo(v1.x);
        acc[1] += w0 * bfhi(v0.x) + w1 * bfhi(v1.x);
        acc[2] += w0 * bflo(v0.y) + w1 * bflo(v1.y);
        acc[3] += w0 * bfhi(v0.y) + w1 * bfhi(v1.y);
        acc[4] += w0 * bflo(v0.z) + w1 * bflo(v1.z);
        acc[5] += w0 * bfhi(v0.z) + w1 * bfhi(v1.z);
        acc[6] += w0 * bflo(v0.w) + w1 * bflo(v1.w);
        acc[7] += w0 * bfhi(v0.w) + w1 * bfhi(v1.w);
    }
    for (; k < dm; k += 4) {                 // tail: up to 4 edges, masked per subgroup
        int e = k + sg;
        if (e < dm) {
            int s = bk[e];
            uint4 v = xpb4[(unsigned)s * 16 + sl];
            float w = __expf(lrelu(a_src[(unsigned)s * 8 + h] + adh));
            sm += w;
            acc[0] += w * bflo(v.x); acc[1] += w * bfhi(v.x);
            acc[2] += w * bflo(v.y); acc[3] += w * bfhi(v.y);
            acc[4] += w * bflo(v.z); acc[5] += w * bfhi(v.z);
            acc[6] += w * bflo(v.w); acc[7] += w * bfhi(v.w);
        }
    }
    if (deg > KCAP) {                        // rare overflow path
        int novf = *ovfc;
        if (novf > OVF_CAP) novf = OVF_CAP;
        for (int o = sg; o < novf; o += 4) {
            if (ovf[2 * o] == node) {
                int s = ovf[2 * o + 1];
                uint4 v = xpb4[(unsigned)s * 16 + sl];
                float w = __expf(lrelu(a_src[(unsigned)s * 8 + h] + adh));
                sm += w;
                acc[0] += w * bflo(v.x); acc[1] += w * bfhi(v.x);
                acc[2] += w * bflo(v.y); acc[3] += w * bfhi(v.y);
                acc[4] += w * bflo(v.z); acc[5] += w * bfhi(v.z);
                acc[6] += w * bflo(v.w); acc[7] += w * bfhi(v.w);
            }
        }
    }

    // combine the 4 subgroup partials (sl preserved under xor 16/32)
    sm += __shfl_xor(sm, 16);
    sm += __shfl_xor(sm, 32);
#pragma unroll
    for (int i = 0; i < 8; ++i) {
        acc[i] += __shfl_xor(acc[i], 16);
        acc[i] += __shfl_xor(acc[i], 32);
    }

    if (sg == 0) {
        float rd = 1.f / (sm + 1e-16f);
        int j = sl * 8;
        float4 b0 = *(const float4*)&bias[j];
        float4 b1 = *(const float4*)&bias[j + 4];
        *(float4*)&out[(unsigned)node * 128 + j] =
            make_float4(acc[0] * rd + b0.x, acc[1] * rd + b0.y, acc[2] * rd + b0.z, acc[3] * rd + b0.w);
        *(float4*)&out[(unsigned)node * 128 + j + 4] =
            make_float4(acc[4] * rd + b1.x, acc[5] * rd + b1.y, acc[6] * rd + b1.z, acc[7] * rd + b1.w);
    }
}

extern "C" void kernel_launch(void* const* d_in, const int* in_sizes, int n_in,
                              void* d_out, int out_size, void* d_ws, size_t ws_size,
                              hipStream_t stream) {
    const float* x = (const float*)d_in[0];
    const int* ei = (const int*)d_in[1];          // int32 (harness-converted)
    const float* W = (const float*)d_in[2];
    const float* att_src = (const float*)d_in[3];
    const float* att_dst = (const float*)d_in[4];
    const float* bias = (const float*)d_in[5];

    int N = in_sizes[0] / 128;   // 100000
    int E = in_sizes[1] / 2;     // 1600000
    float* out = (float*)d_out;

    int pw8 = (N + 7) / 8;       // 12500

    // ws layout (4B units): xpb[N*64] | a_src[N*8] | a_dst[N*8]
    //                      | count[N] | ovfc[1] | ovf[2*OVF_CAP] | bucket[N*KCAP]
    unsigned* xpb = (unsigned*)d_ws;
    float* a_src = (float*)(xpb + (size_t)N * 64);
    float* a_dst = a_src + (size_t)N * 8;
    int* count = (int*)(a_dst + (size_t)N * 8);
    int* ovfc = count + N;       // zeroed by k_gemm (g == N)
    int* ovf = ovfc + 1;
    int* bucket = ovf + 2 * OVF_CAP;

    k_gemm<<<(N + 127) / 128, 256, 0, stream>>>(x, W, att_src, att_dst,
                                                xpb, a_src, a_dst, count, N);
    k_scatter<<<8192, 256, 0, stream>>>(ei, count, bucket, ovfc, ovf, E, pw8, N);
    k_aggr<<<8 * ((pw8 + 3) / 4), 256, 0, stream>>>((const uint4*)xpb, a_src, a_dst, count,
                                                    bucket, ovfc, ovf, bias, out, N, pw8);
}

// Round 16
// 171.656 us; speedup vs baseline: 1.1599x; 1.0867x over previous
//
#include <hip/hip_runtime.h>
#include <math.h>

// GAT single layer: N=100000, E=1.6M, F_IN=128, H=8, C=16 (HC=128)
// R16: interleaved fusion of gemm+scatter. Groups of 8 blocks; group g is
// gemm iff g%12==0 (R9's fusion failed because gemm blocks were all FIRST ->
// no resident overlap; interleaving fixes the mix). res=bid&7 preserved for
// XCD-owned scatter. prep separate (R15 showed per-block prep costs more
// than it saves). k_aggr = proven R11 version.

#define KCAP 32
#define OVF_CAP 65536
#define NGROUPS 1176     // 98 gemm groups (784 blocks) + 1078 scatter groups
#define NSCAT 1078

typedef __attribute__((ext_vector_type(8))) short short8;    // 8 bf16 (4 VGPR)
typedef __attribute__((ext_vector_type(4))) float f32x4;     // MFMA acc

__device__ __forceinline__ float lrelu(float x) { return x > 0.f ? x : 0.2f * x; }

__device__ __forceinline__ unsigned short f2bf(float f) {   // RNE
    unsigned u = __float_as_uint(f);
    unsigned r = u + 0x7FFFu + ((u >> 16) & 1u);
    return (unsigned short)(r >> 16);
}
__device__ __forceinline__ float bflo(unsigned v) { return __uint_as_float(v << 16); }
__device__ __forceinline__ float bfhi(unsigned v) { return __uint_as_float(v & 0xffff0000u); }

// ---------------- prep: Wcat[144][128] bf16 + zero count/ovfc ----------------
__global__ void k_prep(const float* __restrict__ W, const float* __restrict__ att_src,
                       const float* __restrict__ att_dst, unsigned short* __restrict__ wtg,
                       int* __restrict__ count, int N) {
    int t = blockIdx.x * blockDim.x + threadIdx.x;
    if (t <= N) count[t] = 0;          // count[N] doubles as ovfc
    if (t >= 144 * 128) return;
    int row = t >> 7, k = t & 127;
    float val;
    if (row < 128) {
        val = W[k * 128 + row];                       // transpose
    } else if (row < 136) {
        int h = row - 128; val = 0.f;
#pragma unroll
        for (int c = 0; c < 16; ++c) val += W[k * 128 + h * 16 + c] * att_src[h * 16 + c];
    } else {
        int h = row - 136; val = 0.f;
#pragma unroll
        for (int c = 0; c < 16; ++c) val += W[k * 128 + h * 16 + c] * att_dst[h * 16 + c];
    }
    wtg[row * 128 + k] = f2bf(val);
}

// ---------------- fused: interleaved MFMA GEMM + XCD-owned scatter ----------------
__global__ __launch_bounds__(256) void k_fused(const float* __restrict__ x,
                                               const unsigned* __restrict__ wtg4,
                                               unsigned* __restrict__ xpb,
                                               float* __restrict__ a_src,
                                               float* __restrict__ a_dst, int N,
                                               const int* __restrict__ ei,
                                               int* __restrict__ count,
                                               int* __restrict__ bucket,
                                               int* __restrict__ ovfc,
                                               int* __restrict__ ovf,
                                               int E, int pw8) {
    __shared__ __align__(16) unsigned short Wl[144 * 136];   // +8 bf16 pad per row

    int g = blockIdx.x >> 3;
    int r8 = blockIdx.x & 7;

    if (g % 12 != 0) {
        // ---- scatter path: residue r8 owns dst range [r8*pw8, (r8+1)*pw8) ----
        int dlo = r8 * pw8, dhi = dlo + pw8;
        if (dhi > N) dhi = N;
        int sub = g - g / 12 - 1;            // enumeration of scatter groups
        long stride = (long)NSCAT * 256 * 4;
        for (long e = ((long)sub * 256 + threadIdx.x) * 4; e < E; e += stride) {
            int4 d4 = *(const int4*)&ei[E + e];
            int4 s4 = *(const int4*)&ei[e];
#pragma unroll
            for (int c = 0; c < 4; ++c) {
                int d = (&d4.x)[c];
                if (d >= dlo && d < dhi) {
                    int s = (&s4.x)[c];
                    int slot = atomicAdd(&count[d], 1);
                    if (slot < KCAP) {
                        bucket[(unsigned)d * KCAP + slot] = s;
                    } else {
                        int o = atomicAdd(ovfc, 1);
                        if (o < OVF_CAP) { ovf[2 * o] = d; ovf[2 * o + 1] = s; }
                    }
                }
            }
        }
        return;
    }

    // ---- gemm path: tile index from gemm-group enumeration ----
    int tile = (g / 12) * 8 + r8;            // 0..783 (782,783 stage-only no-ops)
    int tid = threadIdx.x;
    uint4* l4 = (uint4*)Wl;
    const uint4* g4 = (const uint4*)wtg4;
#pragma unroll
    for (int it = 0; it < 9; ++it) {
        int idx = tid + it * 256;          // < 2304
        int row = idx >> 4, c = idx & 15;
        l4[row * 17 + c] = g4[idx];
    }
    __syncthreads();

    int w = tid >> 6, lane = tid & 63;
    int col = lane & 15, grp = lane >> 4;

#pragma unroll 1
    for (int rt = 0; rt < 2; ++rt) {
        int r0 = tile * 128 + rt * 64 + w * 16;
        if (r0 >= N) break;                // wave-uniform; no barriers inside loop
        int arow = r0 + col;
        int arc = arow < N ? arow : N - 1;

        f32x4 acc[9];
#pragma unroll
        for (int t = 0; t < 9; ++t) acc[t] = (f32x4){0.f, 0.f, 0.f, 0.f};

#pragma unroll
        for (int kk = 0; kk < 4; ++kk) {
            int k0 = kk * 32 + grp * 8;
            float4 xa = *(const float4*)&x[(long)arc * 128 + k0];
            float4 xb = *(const float4*)&x[(long)arc * 128 + k0 + 4];
            short8 a;
            a[0] = (short)f2bf(xa.x); a[1] = (short)f2bf(xa.y);
            a[2] = (short)f2bf(xa.z); a[3] = (short)f2bf(xa.w);
            a[4] = (short)f2bf(xb.x); a[5] = (short)f2bf(xb.y);
            a[6] = (short)f2bf(xb.z); a[7] = (short)f2bf(xb.w);
#pragma unroll
            for (int t = 0; t < 9; ++t) {
                short8 b = *(const short8*)&Wl[(t * 16 + col) * 136 + k0];
                acc[t] = __builtin_amdgcn_mfma_f32_16x16x32_bf16(a, b, acc[t], 0, 0, 0);
            }
        }

        // epilogue: tiles 0-7 -> packed bf16 xpb; tile 8 -> a_src/a_dst
#pragma unroll
        for (int t = 0; t < 8; ++t) {
#pragma unroll
            for (int reg = 0; reg < 4; ++reg) {
                float mine = acc[t][reg];
                float oth = __shfl_xor(mine, 1);
                unsigned mb = f2bf(mine), ob = f2bf(oth);
                unsigned dw = (lane & 1) ? (ob | (mb << 16)) : (mb | (ob << 16));
                if (((lane & 1) == 0 && reg < 2) || ((lane & 1) == 1 && reg >= 2)) {
                    int grow = r0 + grp * 4 + reg;
                    if (grow < N) xpb[(unsigned)grow * 64 + t * 8 + (col >> 1)] = dw;
                }
            }
        }
#pragma unroll
        for (int reg = 0; reg < 4; ++reg) {
            int grow = r0 + grp * 4 + reg;
            if (grow < N) {
                float v = acc[8][reg];
                if (col < 8) a_src[(unsigned)grow * 8 + col] = v;
                else         a_dst[(unsigned)grow * 8 + (col - 8)] = v;
            }
        }
    }
}

// ---------------- fused softmax+aggregation: 16 lanes/edge, 4 nodes/block ----------------
__global__ __launch_bounds__(256) void k_aggr(const uint4* __restrict__ xpb4,
                                              const float* __restrict__ a_src,
                                              const float* __restrict__ a_dst,
                                              const int* __restrict__ count,
                                              const int* __restrict__ bucket,
                                              const int* __restrict__ ovfc,
                                              const int* __restrict__ ovf,
                                              const float* __restrict__ bias,
                                              float* __restrict__ out, int N, int pw8) {
    int wv = threadIdx.x >> 6, lane = threadIdx.x & 63;
    int res = blockIdx.x & 7, sub = blockIdx.x >> 3;
    int nir = sub * 4 + wv;                  // node index within this residue's range
    if (nir >= pw8) return;
    int node = res * pw8 + nir;
    if (node >= N) return;

    int deg = count[node];
    const int* bk = &bucket[(unsigned)node * KCAP];

    int sg = lane >> 4, sl = lane & 15;      // subgroup (edge slot), sub-lane (feature block)
    int h = sl >> 1;                         // head for features sl*8..sl*8+7
    float adh = a_dst[(unsigned)node * 8 + h];

    float acc[8];
#pragma unroll
    for (int i = 0; i < 8; ++i) acc[i] = 0.f;
    float sm = 0.f;

    int dm = deg < KCAP ? deg : KCAP;
    int k = 0;
    for (; k + 16 <= dm; k += 16) {          // 16 edges: 4 per subgroup
        int e0 = bk[k + sg], e1 = bk[k + 4 + sg], e2 = bk[k + 8 + sg], e3 = bk[k + 12 + sg];
        uint4 v0 = xpb4[(unsigned)e0 * 16 + sl];
        uint4 v1 = xpb4[(unsigned)e1 * 16 + sl];
        uint4 v2 = xpb4[(unsigned)e2 * 16 + sl];
        uint4 v3 = xpb4[(unsigned)e3 * 16 + sl];
        float w0 = __expf(lrelu(a_src[(unsigned)e0 * 8 + h] + adh));
        float w1 = __expf(lrelu(a_src[(unsigned)e1 * 8 + h] + adh));
        float w2 = __expf(lrelu(a_src[(unsigned)e2 * 8 + h] + adh));
        float w3 = __expf(lrelu(a_src[(unsigned)e3 * 8 + h] + adh));
        sm += (w0 + w1) + (w2 + w3);
        acc[0] += w0 * bflo(v0.x) + w1 * bflo(v1.x) + w2 * bflo(v2.x) + w3 * bflo(v3.x);
        acc[1] += w0 * bfhi(v0.x) + w1 * bfhi(v1.x) + w2 * bfhi(v2.x) + w3 * bfhi(v3.x);
        acc[2] += w0 * bflo(v0.y) + w1 * bflo(v1.y) + w2 * bflo(v2.y) + w3 * bflo(v3.y);
        acc[3] += w0 * bfhi(v0.y) + w1 * bfhi(v1.y) + w2 * bfhi(v2.y) + w3 * bfhi(v3.y);
        acc[4] += w0 * bflo(v0.z) + w1 * bflo(v1.z) + w2 * bflo(v2.z) + w3 * bflo(v3.z);
        acc[5] += w0 * bfhi(v0.z) + w1 * bfhi(v1.z) + w2 * bfhi(v2.z) + w3 * bfhi(v3.z);
        acc[6] += w0 * bflo(v0.w) + w1 * bflo(v1.w) + w2 * bflo(v2.w) + w3 * bflo(v3.w);
        acc[7] += w0 * bfhi(v0.w) + w1 * bfhi(v1.w) + w2 * bfhi(v2.w) + w3 * bfhi(v3.w);
    }
    for (; k + 8 <= dm; k += 8) {            // 8 edges: 2 per subgroup
        int e0 = bk[k + sg], e1 = bk[k + 4 + sg];
        uint4 v0 = xpb4[(unsigned)e0 * 16 + sl];
        uint4 v1 = xpb4[(unsigned)e1 * 16 + sl];
        float w0 = __expf(lrelu(a_src[(unsigned)e0 * 8 + h] + adh));
        float w1 = __expf(lrelu(a_src[(unsigned)e1 * 8 + h] + adh));
        sm += w0 + w1;
        acc[0] += w0 * bflo(v0.x) + w1 * bflo(v1.x);
        acc[1] += w0 * bfhi(v0.x) + w1 * bfhi(v1.x);
        acc[2] += w0 * bflo(v0.y) + w1 * bflo(v1.y);
        acc[3] += w0 * bfhi(v0.y) + w1 * bfhi(v1.y);
        acc[4] += w0 * bflo(v0.z) + w1 * bflo(v1.z);
        acc[5] += w0 * bfhi(v0.z) + w1 * bfhi(v1.z);
        acc[6] += w0 * bflo(v0.w) + w1 * bflo(v1.w);
        acc[7] += w0 * bfhi(v0.w) + w1 * bfhi(v1.w);
    }
    for (; k < dm; k += 4) {                 // tail: up to 4 edges, masked per subgroup
        int e = k + sg;
        if (e < dm) {
            int s = bk[e];
            uint4 v = xpb4[(unsigned)s * 16 + sl];
            float w = __expf(lrelu(a_src[(unsigned)s * 8 + h] + adh));
            sm += w;
            acc[0] += w * bflo(v.x); acc[1] += w * bfhi(v.x);
            acc[2] += w * bflo(v.y); acc[3] += w * bfhi(v.y);
            acc[4] += w * bflo(v.z); acc[5] += w * bfhi(v.z);
            acc[6] += w * bflo(v.w); acc[7] += w * bfhi(v.w);
        }
    }
    if (deg > KCAP) {                        // rare overflow path
        int novf = *ovfc;
        if (novf > OVF_CAP) novf = OVF_CAP;
        for (int o = sg; o < novf; o += 4) {
            if (ovf[2 * o] == node) {
                int s = ovf[2 * o + 1];
                uint4 v = xpb4[(unsigned)s * 16 + sl];
                float w = __expf(lrelu(a_src[(unsigned)s * 8 + h] + adh));
                sm += w;
                acc[0] += w * bflo(v.x); acc[1] += w * bfhi(v.x);
                acc[2] += w * bflo(v.y); acc[3] += w * bfhi(v.y);
                acc[4] += w * bflo(v.z); acc[5] += w * bfhi(v.z);
                acc[6] += w * bflo(v.w); acc[7] += w * bfhi(v.w);
            }
        }
    }

    // combine the 4 subgroup partials (sl preserved under xor 16/32)
    sm += __shfl_xor(sm, 16);
    sm += __shfl_xor(sm, 32);
#pragma unroll
    for (int i = 0; i < 8; ++i) {
        acc[i] += __shfl_xor(acc[i], 16);
        acc[i] += __shfl_xor(acc[i], 32);
    }

    if (sg == 0) {
        float rd = 1.f / (sm + 1e-16f);
        int j = sl * 8;
        float4 b0 = *(const float4*)&bias[j];
        float4 b1 = *(const float4*)&bias[j + 4];
        *(float4*)&out[(unsigned)node * 128 + j] =
            make_float4(acc[0] * rd + b0.x, acc[1] * rd + b0.y, acc[2] * rd + b0.z, acc[3] * rd + b0.w);
        *(float4*)&out[(unsigned)node * 128 + j + 4] =
            make_float4(acc[4] * rd + b1.x, acc[5] * rd + b1.y, acc[6] * rd + b1.z, acc[7] * rd + b1.w);
    }
}

extern "C" void kernel_launch(void* const* d_in, const int* in_sizes, int n_in,
                              void* d_out, int out_size, void* d_ws, size_t ws_size,
                              hipStream_t stream) {
    const float* x = (const float*)d_in[0];
    const int* ei = (const int*)d_in[1];          // int32 (harness-converted)
    const float* W = (const float*)d_in[2];
    const float* att_src = (const float*)d_in[3];
    const float* att_dst = (const float*)d_in[4];
    const float* bias = (const float*)d_in[5];

    int N = in_sizes[0] / 128;   // 100000
    int E = in_sizes[1] / 2;     // 1600000
    float* out = (float*)d_out;

    int pw8 = (N + 7) / 8;       // 12500

    // ws layout (4B units): xpb[N*64] | a_src[N*8] | a_dst[N*8] | wtg[4608 dwords]
    //                      | count[N] | ovfc[1] | ovf[2*OVF_CAP] | bucket[N*KCAP]
    unsigned* xpb = (unsigned*)d_ws;
    float* a_src = (float*)(xpb + (size_t)N * 64);
    float* a_dst = a_src + (size_t)N * 8;
    unsigned short* wtg = (unsigned short*)(a_dst + (size_t)N * 8);
    int* count = (int*)(wtg + 144 * 128);
    int* ovfc = count + N;       // zeroed by k_prep
    int* ovf = ovfc + 1;
    int* bucket = ovf + 2 * OVF_CAP;

    k_prep<<<463, 256, 0, stream>>>(W, att_src, att_dst, wtg, count, N);
    k_fused<<<NGROUPS * 8, 256, 0, stream>>>(x, (const unsigned*)wtg, xpb, a_src, a_dst, N,
                                             ei, count, bucket, ovfc, ovf, E, pw8);
    k_aggr<<<8 * ((pw8 + 3) / 4), 256, 0, stream>>>((const uint4*)xpb, a_src, a_dst, count,
                                                    bucket, ovfc, ovf, bias, out, N, pw8);
}